// Round 2
// baseline (2003.179 us; speedup 1.0000x reference)
//
#include <hip/hip_runtime.h>
#include <hip/hip_bf16.h>

typedef unsigned short u16;
typedef unsigned int u32;

#define BATCH 4
#define NHIST 4
#define NPART 1000
#define NTOPK 10
#define NPT (BATCH*NPART)     // 4000 particles total
#define NET (NPT*NTOPK)       // 40000 edges total

__device__ __forceinline__ float bf2f(u16 b){
    return __uint_as_float(((u32)b) << 16);
}
__device__ __forceinline__ u16 f2bf(float f){
    u32 u = __float_as_uint(f);
    u32 r = u + 0x7FFF + ((u >> 16) & 1);  // RNE
    return (u16)(r >> 16);
}
// dtype-agnostic input read: element i as float, per runtime flag
__device__ __forceinline__ float ldin(const void* p, size_t i, int isf32){
    return isf32 ? ((const float*)p)[i] : bf2f(((const u16*)p)[i]);
}

// ---------------- dtype probe: a_hist is Uniform[0,1) ----------------
// bf16 encoding of [0,1) never sets bit15; fp32 low-halves are ~uniform u16.
__global__ void k_detect(const void* __restrict__ a_hist, int nu16, int* __restrict__ dflag)
{
    __shared__ int s;
    int t = threadIdx.x;
    if (t == 0) s = 0;
    __syncthreads();
    const u16* p = (const u16*)a_hist;
    int bad = 0;
    for (int i = t; i < nu16; i += 256) bad |= (p[i] & 0x8000) ? 1 : 0;
    if (bad) atomicOr(&s, 1);
    __syncthreads();
    if (t == 0) dflag[0] = s;   // 1 => inputs are float32
}

// ---------------- prep: a_cur, s_cur, pe_in ----------------
__global__ void k_prep(const void* __restrict__ a_hist, const void* __restrict__ s_hist,
                       const void* __restrict__ s_delta, const int* __restrict__ dflag,
                       float* __restrict__ a_cur, float* __restrict__ s_cur,
                       float* __restrict__ pe_in)
{
    int g = blockIdx.x * 256 + threadIdx.x;
    if (g >= NPT) return;
    int isf32 = dflag[0];
    int b = g / NPART, i = g - b * NPART;
    a_cur[g] = ldin(a_hist, (b*NHIST + NHIST-1)*NPART + i, isf32);
    #pragma unroll
    for (int d = 0; d < 3; d++)
        s_cur[g*3 + d] = ldin(s_hist, (size_t)((b*NHIST + NHIST-1)*NPART + i)*3 + d, isf32);
    #pragma unroll
    for (int h = 0; h < NHIST; h++){
        #pragma unroll
        for (int d = 0; d < 3; d++)
            pe_in[g*16 + h*3 + d] = ldin(s_delta, (size_t)((b*NHIST + h)*NPART + i)*3 + d, isf32);
        pe_in[g*16 + 12 + h] = ldin(a_hist, (b*NHIST + h)*NPART + i, isf32);
    }
}

// ---------------- topk edge construction ----------------
__global__ __launch_bounds__(256) void k_topk(const float* __restrict__ a_cur,
        const float* __restrict__ s_cur,
        int* __restrict__ send, float* __restrict__ flag, float* __restrict__ re_in)
{
    __shared__ float sx[NPART], sy[NPART], sz[NPART], sa[NPART];
    int b = blockIdx.x >> 2;        // 4 blocks per batch
    int chunk = blockIdx.x & 3;
    int t = threadIdx.x;
    for (int j = t; j < NPART; j += 256){
        int g = b*NPART + j;
        sx[j] = s_cur[g*3+0]; sy[j] = s_cur[g*3+1]; sz[j] = s_cur[g*3+2];
        sa[j] = a_cur[g];
    }
    __syncthreads();
    int i = chunk*256 + t;
    if (i >= NPART) return;
    float xi = sx[i], yi = sy[i], zi = sz[i];
    bool tool_i = sa[i] > 0.5f;
    float bd[NTOPK]; int bidx[NTOPK];
    #pragma unroll
    for (int k = 0; k < NTOPK; k++){ bd[k] = 3.0e38f; bidx[k] = 0; }
    for (int j = 0; j < NPART; j++){
        float dx = xi - sx[j], dy = yi - sy[j], dz = zi - sz[j];
        float d = dx*dx + dy*dy + dz*dz;
        if (tool_i && (sa[j] > 0.5f)) d = 1.0e10f;
        if (d < bd[NTOPK-1]){
            float v = d; int vi = j;
            #pragma unroll
            for (int k = 0; k < NTOPK; k++){
                bool sw = v < bd[k];
                float tv = bd[k]; int ti = bidx[k];
                if (sw){ bd[k] = v; bidx[k] = vi; v = tv; vi = ti; }
            }
        }
    }
    float ai = sa[i];
    int gp = b*NPART + i;
    #pragma unroll
    for (int k = 0; k < NTOPK; k++){
        int re = gp*NTOPK + k;
        int j = bidx[k];
        float fl = (!tool_i && bd[k] < 0.25f) ? 1.0f : 0.0f;
        send[re] = b*NPART + j;
        flag[re] = fl;
        float* row = re_in + (size_t)re * 8;
        row[0] = fl * ai;
        row[1] = fl * sa[j];
        row[2] = fl * (xi - sx[j]);
        row[3] = fl * (yi - sy[j]);
        row[4] = fl * (zi - sz[j]);
        row[5] = 0.f; row[6] = 0.f; row[7] = 0.f;
    }
}

// ---------------- generic fused GEMM: C = relu(A_gathered @ W + b [+ res]) ----------------
// N fixed at 256 output cols. AMODE: 0=direct (lda), 1=RP gather (K=768), 2=PP concat (K=512)
#define TM 64
template<int AMODE, bool RES>
__global__ __launch_bounds__(256) void k_gemm(
    const float* __restrict__ A, const float* __restrict__ X1,
    const int* __restrict__ send,
    const void* __restrict__ W, const void* __restrict__ Wb,
    const int* __restrict__ dflag,
    const float* __restrict__ res,
    float* __restrict__ C, int M, int K, int KW, int lda)
{
    __shared__ float a_sh[32][68];
    __shared__ float w_sh[32][256];
    const int isf32 = dflag[0];
    int t = threadIdx.x;
    int row0 = blockIdx.x * TM;
    int r0 = (t >> 5) * 8;          // 8 rows per thread
    int ca = (t & 31) * 4;          // cols ca..ca+3 and ca+128..ca+131
    int cb = ca + 128;
    float acc[8][8];
    #pragma unroll
    for (int i = 0; i < 8; i++)
        #pragma unroll
        for (int j = 0; j < 8; j++) acc[i][j] = 0.f;

    int nkc = (K + 31) >> 5;
    for (int kc = 0; kc < nkc; kc++){
        int kbase = kc * 32;
        // stage A tile (64 rows x 32 k), transposed into LDS
        #pragma unroll
        for (int li = t; li < 512; li += 256){
            int row = li >> 3;
            int kq = (li & 7) * 4;
            int kg = kbase + kq;
            int rg = row0 + row; if (rg >= M) rg = M - 1;
            float4 v = make_float4(0.f, 0.f, 0.f, 0.f);
            if (kg < K){
                const float* src;
                if (AMODE == 0){
                    src = A + (size_t)rg * lda + kg;
                } else if (AMODE == 1){
                    if (kg < 256)      src = A  + (size_t)rg * 256 + kg;
                    else if (kg < 512) src = X1 + (size_t)(rg/10) * 256 + (kg - 256);
                    else               src = X1 + (size_t)send[rg] * 256 + (kg - 512);
                } else {
                    if (kg < 256)      src = A  + (size_t)rg * 256 + kg;
                    else               src = X1 + (size_t)rg * 256 + (kg - 256);
                }
                v = *(const float4*)src;
            }
            a_sh[kq+0][row] = v.x; a_sh[kq+1][row] = v.y;
            a_sh[kq+2][row] = v.z; a_sh[kq+3][row] = v.w;
        }
        // stage W tile (32 k x 256 cols), dtype-agnostic -> f32
        #pragma unroll
        for (int li = t; li < 2048; li += 256){
            int k  = li >> 6;
            int c4 = (li & 63) * 4;
            int kg = kbase + k;
            float4 v = make_float4(0.f, 0.f, 0.f, 0.f);
            if (kg < KW){
                if (isf32){
                    v = *(const float4*)((const float*)W + (size_t)kg * 256 + c4);
                } else {
                    ushort4 wv = *(const ushort4*)((const u16*)W + (size_t)kg * 256 + c4);
                    v.x = bf2f(wv.x); v.y = bf2f(wv.y); v.z = bf2f(wv.z); v.w = bf2f(wv.w);
                }
            }
            *(float4*)&w_sh[k][c4] = v;
        }
        __syncthreads();
        #pragma unroll 8
        for (int k = 0; k < 32; k++){
            float4 a0 = *(const float4*)&a_sh[k][r0];
            float4 a1 = *(const float4*)&a_sh[k][r0+4];
            float4 w0 = *(const float4*)&w_sh[k][ca];
            float4 w1 = *(const float4*)&w_sh[k][cb];
            float av[8] = {a0.x,a0.y,a0.z,a0.w,a1.x,a1.y,a1.z,a1.w};
            float wv[8] = {w0.x,w0.y,w0.z,w0.w,w1.x,w1.y,w1.z,w1.w};
            #pragma unroll
            for (int i = 0; i < 8; i++)
                #pragma unroll
                for (int j = 0; j < 8; j++)
                    acc[i][j] += av[i] * wv[j];
        }
        __syncthreads();
    }
    // epilogue
    float bia[8];
    if (isf32){
        float4 b0 = *(const float4*)((const float*)Wb + ca);
        float4 b1 = *(const float4*)((const float*)Wb + cb);
        bia[0]=b0.x; bia[1]=b0.y; bia[2]=b0.z; bia[3]=b0.w;
        bia[4]=b1.x; bia[5]=b1.y; bia[6]=b1.z; bia[7]=b1.w;
    } else {
        ushort4 b0 = *(const ushort4*)((const u16*)Wb + ca);
        ushort4 b1 = *(const ushort4*)((const u16*)Wb + cb);
        bia[0]=bf2f(b0.x); bia[1]=bf2f(b0.y); bia[2]=bf2f(b0.z); bia[3]=bf2f(b0.w);
        bia[4]=bf2f(b1.x); bia[5]=bf2f(b1.y); bia[6]=bf2f(b1.z); bia[7]=bf2f(b1.w);
    }
    #pragma unroll
    for (int i = 0; i < 8; i++){
        int rg = row0 + r0 + i;
        if (rg >= M) continue;
        float out[8];
        #pragma unroll
        for (int j = 0; j < 8; j++){
            float v = acc[i][j] + bia[j];
            if (RES){
                int c = (j < 4) ? (ca + j) : (cb + j - 4);
                v += res[(size_t)rg * 256 + c];
            }
            out[j] = v > 0.f ? v : 0.f;
        }
        *(float4*)&C[(size_t)rg*256 + ca] = make_float4(out[0],out[1],out[2],out[3]);
        *(float4*)&C[(size_t)rg*256 + cb] = make_float4(out[4],out[5],out[6],out[7]);
    }
}

// ---------------- agg: per-particle flag-masked sum over its 10 edges ----------------
__global__ void k_agg(const float* __restrict__ effect_rel, const float* __restrict__ flag,
                      float* __restrict__ agg)
{
    int g = blockIdx.x;
    int c = threadIdx.x;
    float s = 0.f;
    #pragma unroll
    for (int k = 0; k < NTOPK; k++){
        float f = flag[g*NTOPK + k];
        if (f > 0.f)
            s += effect_rel[(size_t)(g*NTOPK + k) * 256 + c];
    }
    agg[(size_t)g*256 + c] = s;
}

// ---------------- final: predh @ pr_w1 + pr_b1 + s_cur -> out (dtype per flag) ----------------
__global__ void k_final(const float* __restrict__ ph, const void* __restrict__ w1,
                        const void* __restrict__ b1, const int* __restrict__ dflag,
                        const float* __restrict__ s_cur, void* __restrict__ out)
{
    int idx = blockIdx.x * 256 + threadIdx.x;
    if (idx >= NPT * 3) return;
    int isf32 = dflag[0];
    int g = idx / 3, d = idx - g * 3;
    float s = ldin(b1, d, isf32) + s_cur[idx];
    const float* row = ph + (size_t)g * 256;
    #pragma unroll 8
    for (int k = 0; k < 256; k++)
        s += row[k] * ldin(w1, k*3 + d, isf32);
    if (isf32) ((float*)out)[idx] = s;
    else       ((u16*)out)[idx]   = f2bf(s);
}

extern "C" void kernel_launch(void* const* d_in, const int* in_sizes, int n_in,
                              void* d_out, int out_size, void* d_ws, size_t ws_size,
                              hipStream_t stream) {
    const void* a_hist = d_in[0];
    const void* s_hist = d_in[1];
    const void* s_delta= d_in[2];
    const void* pe_w0 = d_in[3];  const void* pe_b0 = d_in[4];
    const void* pe_w1 = d_in[5];  const void* pe_b1 = d_in[6];
    const void* re_w0 = d_in[7];  const void* re_b0 = d_in[8];
    const void* re_w1 = d_in[9];  const void* re_b1 = d_in[10];
    const void* re_w2 = d_in[11]; const void* re_b2 = d_in[12];
    const void* rp_w  = d_in[13]; const void* rp_b  = d_in[14];
    const void* pp_w  = d_in[15]; const void* pp_b  = d_in[16];
    const void* pr_w0 = d_in[17]; const void* pr_b0 = d_in[18];
    const void* pr_w1 = d_in[19]; const void* pr_b1 = d_in[20];

    float* w = (float*)d_ws;
    size_t off = 0;
    int* dflag   = (int*)w; off += 4;
    float* a_cur = w + off; off += NPT;
    float* s_cur = w + off; off += NPT*3;
    float* pe_in = w + off; off += (size_t)NPT*16;
    float* re_in = w + off; off += (size_t)NET*8;
    float* flagp = w + off; off += NET;
    int*   send  = (int*)(w + off); off += NET;
    float* hp    = w + off; off += (size_t)NPT*256;
    float* penc  = w + off; off += (size_t)NPT*256;
    float* agg   = w + off; off += (size_t)NPT*256;
    float* peffA = w + off; off += (size_t)NPT*256;
    float* peffB = w + off; off += (size_t)NPT*256;
    float* predh = w + off; off += (size_t)NPT*256;
    float* E1    = w + off; off += (size_t)NET*256;   // rel_enc (persistent)
    float* E2    = w + off; off += (size_t)NET*256;   // effect_rel / temp

    const int gP = (NPT + TM - 1) / TM;   // 63 blocks for particle GEMMs
    const int gE = (NET + TM - 1) / TM;   // 625 blocks for edge GEMMs

    k_detect<<<1, 256, 0, stream>>>(a_hist, 2000, dflag);
    k_prep<<<(NPT + 255)/256, 256, 0, stream>>>(a_hist, s_hist, s_delta, dflag, a_cur, s_cur, pe_in);
    k_topk<<<16, 256, 0, stream>>>(a_cur, s_cur, send, flagp, re_in);

    // particle encoder
    k_gemm<0,false><<<gP, 256, 0, stream>>>(pe_in, nullptr, nullptr, pe_w0, pe_b0, dflag, nullptr, hp,   NPT, 16, 16, 16);
    k_gemm<0,false><<<gP, 256, 0, stream>>>(hp,    nullptr, nullptr, pe_w1, pe_b1, dflag, nullptr, penc, NPT, 256, 256, 256);

    // relation encoder (K=5 padded to 8 in A; W rows masked beyond 5)
    k_gemm<0,false><<<gE, 256, 0, stream>>>(re_in, nullptr, nullptr, re_w0, re_b0, dflag, nullptr, E1, NET, 8, 5, 8);
    k_gemm<0,false><<<gE, 256, 0, stream>>>(E1,    nullptr, nullptr, re_w1, re_b1, dflag, nullptr, E2, NET, 256, 256, 256);
    k_gemm<0,false><<<gE, 256, 0, stream>>>(E2,    nullptr, nullptr, re_w2, re_b2, dflag, nullptr, E1, NET, 256, 256, 256);
    // E1 = relation_encode (persistent across steps)

    // propagation step 1 (particle_effect = penc)
    k_gemm<1,false><<<gE, 256, 0, stream>>>(E1, penc, send, rp_w, rp_b, dflag, nullptr, E2, NET, 768, 768, 0);
    k_agg<<<NPT, 256, 0, stream>>>(E2, flagp, agg);
    k_gemm<2,true><<<gP, 256, 0, stream>>>(penc, agg, nullptr, pp_w, pp_b, dflag, penc, peffA, NPT, 512, 512, 0);
    // step 2
    k_gemm<1,false><<<gE, 256, 0, stream>>>(E1, peffA, send, rp_w, rp_b, dflag, nullptr, E2, NET, 768, 768, 0);
    k_agg<<<NPT, 256, 0, stream>>>(E2, flagp, agg);
    k_gemm<2,true><<<gP, 256, 0, stream>>>(penc, agg, nullptr, pp_w, pp_b, dflag, peffA, peffB, NPT, 512, 512, 0);
    // step 3
    k_gemm<1,false><<<gE, 256, 0, stream>>>(E1, peffB, send, rp_w, rp_b, dflag, nullptr, E2, NET, 768, 768, 0);
    k_agg<<<NPT, 256, 0, stream>>>(E2, flagp, agg);
    k_gemm<2,true><<<gP, 256, 0, stream>>>(penc, agg, nullptr, pp_w, pp_b, dflag, peffB, peffA, NPT, 512, 512, 0);

    // predictor
    k_gemm<0,false><<<gP, 256, 0, stream>>>(peffA, nullptr, nullptr, pr_w0, pr_b0, dflag, nullptr, predh, NPT, 256, 256, 256);
    k_final<<<(NPT*3 + 255)/256, 256, 0, stream>>>(predh, pr_w1, pr_b1, dflag, s_cur, (void*)d_out);
}

// Round 3
// 1507.465 us; speedup vs baseline: 1.3288x; 1.3288x over previous
//
#include <hip/hip_runtime.h>
#include <hip/hip_bf16.h>

typedef unsigned short u16;
typedef unsigned int u32;

#define BATCH 4
#define NHIST 4
#define NPART 1000
#define NTOPK 10
#define NPT (BATCH*NPART)     // 4000 particles total
#define NET (NPT*NTOPK)       // 40000 edges total

__device__ __forceinline__ float bf2f(u16 b){
    return __uint_as_float(((u32)b) << 16);
}
__device__ __forceinline__ u16 f2bf(float f){
    u32 u = __float_as_uint(f);
    u32 r = u + 0x7FFF + ((u >> 16) & 1);  // RNE
    return (u16)(r >> 16);
}
// dtype-agnostic input read: element i as float, per runtime flag
__device__ __forceinline__ float ldin(const void* p, size_t i, int isf32){
    return isf32 ? ((const float*)p)[i] : bf2f(((const u16*)p)[i]);
}

// ---------------- dtype probe: a_hist is Uniform[0,1) ----------------
// bf16 encoding of [0,1) never sets bit15; fp32 low-halves are ~uniform u16.
__global__ void k_detect(const void* __restrict__ a_hist, int nu16, int* __restrict__ dflag)
{
    __shared__ int s;
    int t = threadIdx.x;
    if (t == 0) s = 0;
    __syncthreads();
    const u16* p = (const u16*)a_hist;
    int bad = 0;
    for (int i = t; i < nu16; i += 256) bad |= (p[i] & 0x8000) ? 1 : 0;
    if (bad) atomicOr(&s, 1);
    __syncthreads();
    if (t == 0) dflag[0] = s;   // 1 => inputs are float32
}

// ---------------- prep: a_cur, s_cur, pe_in ----------------
__global__ void k_prep(const void* __restrict__ a_hist, const void* __restrict__ s_hist,
                       const void* __restrict__ s_delta, const int* __restrict__ dflag,
                       float* __restrict__ a_cur, float* __restrict__ s_cur,
                       float* __restrict__ pe_in)
{
    int g = blockIdx.x * 256 + threadIdx.x;
    if (g >= NPT) return;
    int isf32 = dflag[0];
    int b = g / NPART, i = g - b * NPART;
    a_cur[g] = ldin(a_hist, (b*NHIST + NHIST-1)*NPART + i, isf32);
    #pragma unroll
    for (int d = 0; d < 3; d++)
        s_cur[g*3 + d] = ldin(s_hist, (size_t)((b*NHIST + NHIST-1)*NPART + i)*3 + d, isf32);
    #pragma unroll
    for (int h = 0; h < NHIST; h++){
        #pragma unroll
        for (int d = 0; d < 3; d++)
            pe_in[g*16 + h*3 + d] = ldin(s_delta, (size_t)((b*NHIST + h)*NPART + i)*3 + d, isf32);
        pe_in[g*16 + 12 + h] = ldin(a_hist, (b*NHIST + h)*NPART + i, isf32);
    }
}

// ---------------- topk edge construction: one wave per receiver ----------------
// 1000 blocks x 256 threads; block = 4 waves = 4 receivers of one batch
// (250 blocks per batch, 4*250 = 1000 receivers). Per-batch particle tile in LDS.
__global__ __launch_bounds__(256) void k_topk(const float* __restrict__ a_cur,
        const float* __restrict__ s_cur,
        int* __restrict__ send, float* __restrict__ flag, float* __restrict__ re_in)
{
    __shared__ float sx[NPART], sy[NPART], sz[NPART], sa[NPART];
    int b  = blockIdx.x / 250;
    int r0 = (blockIdx.x % 250) * 4;
    int t = threadIdx.x;
    int wid = t >> 6, lane = t & 63;
    for (int j = t; j < NPART; j += 256){
        int g = b*NPART + j;
        sx[j] = s_cur[g*3+0]; sy[j] = s_cur[g*3+1]; sz[j] = s_cur[g*3+2];
        sa[j] = a_cur[g];
    }
    __syncthreads();
    int i = r0 + wid;                 // receiver within batch (< 1000 always)
    float xi = sx[i], yi = sy[i], zi = sz[i];
    float ai = sa[i];
    bool tool_i = ai > 0.5f;

    // per-lane sorted top-10 over strided j (j = lane, lane+64, ...)
    float bd[NTOPK]; int bj[NTOPK];
    #pragma unroll
    for (int k = 0; k < NTOPK; k++){ bd[k] = 3.0e38f; bj[k] = 1 << 30; }
    for (int j = lane; j < NPART; j += 64){
        float dx = xi - sx[j], dy = yi - sy[j], dz = zi - sz[j];
        float d = dx*dx + dy*dy + dz*dz;
        if (tool_i && (sa[j] > 0.5f)) d = 1.0e10f;
        if (d < bd[NTOPK-1]){
            float v = d; int vj = j;
            #pragma unroll
            for (int k = 0; k < NTOPK; k++){
                bool sw = v < bd[k];                 // strict: earlier (smaller) j wins ties
                float tv = bd[k]; int tj = bj[k];
                if (sw){ bd[k] = v; bj[k] = vj; v = tv; vj = tj; }
            }
        }
    }
    // 10-round cross-lane merge: lexicographic (d, j) min matches jax.lax.top_k
    // (lowest index first on ties). Lane r captures round r's winner.
    float myd = 0.f; int myj = 0;
    #pragma unroll
    for (int r = 0; r < NTOPK; r++){
        float v = bd[0]; int vj = bj[0];
        #pragma unroll
        for (int s = 32; s > 0; s >>= 1){
            float ov = __shfl_xor(v, s);
            int   oj = __shfl_xor(vj, s);
            if (ov < v || (ov == v && oj < vj)){ v = ov; vj = oj; }
        }
        if (lane == r){ myd = v; myj = vj; }
        bool owner = (bd[0] == v) && (bj[0] == vj);   // unique: j owned by one lane
        if (owner){
            #pragma unroll
            for (int k = 0; k < NTOPK-1; k++){ bd[k] = bd[k+1]; bj[k] = bj[k+1]; }
            bd[NTOPK-1] = 3.0e38f; bj[NTOPK-1] = 1 << 30;
        }
    }
    if (lane < NTOPK){
        int gp = b*NPART + i;
        int re = gp*NTOPK + lane;
        int j = myj;
        float fl = (!tool_i && myd < 0.25f) ? 1.0f : 0.0f;
        send[re] = b*NPART + j;
        flag[re] = fl;
        float* row = re_in + (size_t)re * 8;
        row[0] = fl * ai;
        row[1] = fl * sa[j];
        row[2] = fl * (xi - sx[j]);
        row[3] = fl * (yi - sy[j]);
        row[4] = fl * (zi - sz[j]);
        row[5] = 0.f; row[6] = 0.f; row[7] = 0.f;
    }
}

// ---------------- generic fused GEMM: C = relu(A_gathered @ W + b [+ res]) ----------------
// N fixed at 256 output cols. AMODE: 0=direct (lda), 1=RP gather (K=768), 2=PP concat (K=512)
#define TM 64
template<int AMODE, bool RES>
__global__ __launch_bounds__(256) void k_gemm(
    const float* __restrict__ A, const float* __restrict__ X1,
    const int* __restrict__ send,
    const void* __restrict__ W, const void* __restrict__ Wb,
    const int* __restrict__ dflag,
    const float* __restrict__ res,
    float* __restrict__ C, int M, int K, int KW, int lda)
{
    __shared__ float a_sh[32][68];
    __shared__ float w_sh[32][256];
    const int isf32 = dflag[0];
    int t = threadIdx.x;
    int row0 = blockIdx.x * TM;
    int r0 = (t >> 5) * 8;          // 8 rows per thread
    int ca = (t & 31) * 4;          // cols ca..ca+3 and ca+128..ca+131
    int cb = ca + 128;
    float acc[8][8];
    #pragma unroll
    for (int i = 0; i < 8; i++)
        #pragma unroll
        for (int j = 0; j < 8; j++) acc[i][j] = 0.f;

    int nkc = (K + 31) >> 5;
    for (int kc = 0; kc < nkc; kc++){
        int kbase = kc * 32;
        // stage A tile (64 rows x 32 k), transposed into LDS
        #pragma unroll
        for (int li = t; li < 512; li += 256){
            int row = li >> 3;
            int kq = (li & 7) * 4;
            int kg = kbase + kq;
            int rg = row0 + row; if (rg >= M) rg = M - 1;
            float4 v = make_float4(0.f, 0.f, 0.f, 0.f);
            if (kg < K){
                const float* src;
                if (AMODE == 0){
                    src = A + (size_t)rg * lda + kg;
                } else if (AMODE == 1){
                    if (kg < 256)      src = A  + (size_t)rg * 256 + kg;
                    else if (kg < 512) src = X1 + (size_t)(rg/10) * 256 + (kg - 256);
                    else               src = X1 + (size_t)send[rg] * 256 + (kg - 512);
                } else {
                    if (kg < 256)      src = A  + (size_t)rg * 256 + kg;
                    else               src = X1 + (size_t)rg * 256 + (kg - 256);
                }
                v = *(const float4*)src;
            }
            a_sh[kq+0][row] = v.x; a_sh[kq+1][row] = v.y;
            a_sh[kq+2][row] = v.z; a_sh[kq+3][row] = v.w;
        }
        // stage W tile (32 k x 256 cols), dtype-agnostic -> f32
        #pragma unroll
        for (int li = t; li < 2048; li += 256){
            int k  = li >> 6;
            int c4 = (li & 63) * 4;
            int kg = kbase + k;
            float4 v = make_float4(0.f, 0.f, 0.f, 0.f);
            if (kg < KW){
                if (isf32){
                    v = *(const float4*)((const float*)W + (size_t)kg * 256 + c4);
                } else {
                    ushort4 wv = *(const ushort4*)((const u16*)W + (size_t)kg * 256 + c4);
                    v.x = bf2f(wv.x); v.y = bf2f(wv.y); v.z = bf2f(wv.z); v.w = bf2f(wv.w);
                }
            }
            *(float4*)&w_sh[k][c4] = v;
        }
        __syncthreads();
        #pragma unroll 8
        for (int k = 0; k < 32; k++){
            float4 a0 = *(const float4*)&a_sh[k][r0];
            float4 a1 = *(const float4*)&a_sh[k][r0+4];
            float4 w0 = *(const float4*)&w_sh[k][ca];
            float4 w1 = *(const float4*)&w_sh[k][cb];
            float av[8] = {a0.x,a0.y,a0.z,a0.w,a1.x,a1.y,a1.z,a1.w};
            float wv[8] = {w0.x,w0.y,w0.z,w0.w,w1.x,w1.y,w1.z,w1.w};
            #pragma unroll
            for (int i = 0; i < 8; i++)
                #pragma unroll
                for (int j = 0; j < 8; j++)
                    acc[i][j] += av[i] * wv[j];
        }
        __syncthreads();
    }
    // epilogue
    float bia[8];
    if (isf32){
        float4 b0 = *(const float4*)((const float*)Wb + ca);
        float4 b1 = *(const float4*)((const float*)Wb + cb);
        bia[0]=b0.x; bia[1]=b0.y; bia[2]=b0.z; bia[3]=b0.w;
        bia[4]=b1.x; bia[5]=b1.y; bia[6]=b1.z; bia[7]=b1.w;
    } else {
        ushort4 b0 = *(const ushort4*)((const u16*)Wb + ca);
        ushort4 b1 = *(const ushort4*)((const u16*)Wb + cb);
        bia[0]=bf2f(b0.x); bia[1]=bf2f(b0.y); bia[2]=bf2f(b0.z); bia[3]=bf2f(b0.w);
        bia[4]=bf2f(b1.x); bia[5]=bf2f(b1.y); bia[6]=bf2f(b1.z); bia[7]=bf2f(b1.w);
    }
    #pragma unroll
    for (int i = 0; i < 8; i++){
        int rg = row0 + r0 + i;
        if (rg >= M) continue;
        float out[8];
        #pragma unroll
        for (int j = 0; j < 8; j++){
            float v = acc[i][j] + bia[j];
            if (RES){
                int c = (j < 4) ? (ca + j) : (cb + j - 4);
                v += res[(size_t)rg * 256 + c];
            }
            out[j] = v > 0.f ? v : 0.f;
        }
        *(float4*)&C[(size_t)rg*256 + ca] = make_float4(out[0],out[1],out[2],out[3]);
        *(float4*)&C[(size_t)rg*256 + cb] = make_float4(out[4],out[5],out[6],out[7]);
    }
}

// ---------------- agg: per-particle flag-masked sum over its 10 edges ----------------
__global__ void k_agg(const float* __restrict__ effect_rel, const float* __restrict__ flag,
                      float* __restrict__ agg)
{
    int g = blockIdx.x;
    int c = threadIdx.x;
    float s = 0.f;
    #pragma unroll
    for (int k = 0; k < NTOPK; k++){
        float f = flag[g*NTOPK + k];
        if (f > 0.f)
            s += effect_rel[(size_t)(g*NTOPK + k) * 256 + c];
    }
    agg[(size_t)g*256 + c] = s;
}

// ---------------- final: predh @ pr_w1 + pr_b1 + s_cur -> out (dtype per flag) ----------------
__global__ void k_final(const float* __restrict__ ph, const void* __restrict__ w1,
                        const void* __restrict__ b1, const int* __restrict__ dflag,
                        const float* __restrict__ s_cur, void* __restrict__ out)
{
    int idx = blockIdx.x * 256 + threadIdx.x;
    if (idx >= NPT * 3) return;
    int isf32 = dflag[0];
    int g = idx / 3, d = idx - g * 3;
    float s = ldin(b1, d, isf32) + s_cur[idx];
    const float* row = ph + (size_t)g * 256;
    #pragma unroll 8
    for (int k = 0; k < 256; k++)
        s += row[k] * ldin(w1, k*3 + d, isf32);
    if (isf32) ((float*)out)[idx] = s;
    else       ((u16*)out)[idx]   = f2bf(s);
}

extern "C" void kernel_launch(void* const* d_in, const int* in_sizes, int n_in,
                              void* d_out, int out_size, void* d_ws, size_t ws_size,
                              hipStream_t stream) {
    const void* a_hist = d_in[0];
    const void* s_hist = d_in[1];
    const void* s_delta= d_in[2];
    const void* pe_w0 = d_in[3];  const void* pe_b0 = d_in[4];
    const void* pe_w1 = d_in[5];  const void* pe_b1 = d_in[6];
    const void* re_w0 = d_in[7];  const void* re_b0 = d_in[8];
    const void* re_w1 = d_in[9];  const void* re_b1 = d_in[10];
    const void* re_w2 = d_in[11]; const void* re_b2 = d_in[12];
    const void* rp_w  = d_in[13]; const void* rp_b  = d_in[14];
    const void* pp_w  = d_in[15]; const void* pp_b  = d_in[16];
    const void* pr_w0 = d_in[17]; const void* pr_b0 = d_in[18];
    const void* pr_w1 = d_in[19]; const void* pr_b1 = d_in[20];

    float* w = (float*)d_ws;
    size_t off = 0;
    int* dflag   = (int*)w; off += 4;
    float* a_cur = w + off; off += NPT;
    float* s_cur = w + off; off += NPT*3;
    float* pe_in = w + off; off += (size_t)NPT*16;
    float* re_in = w + off; off += (size_t)NET*8;
    float* flagp = w + off; off += NET;
    int*   send  = (int*)(w + off); off += NET;
    float* hp    = w + off; off += (size_t)NPT*256;
    float* penc  = w + off; off += (size_t)NPT*256;
    float* agg   = w + off; off += (size_t)NPT*256;
    float* peffA = w + off; off += (size_t)NPT*256;
    float* peffB = w + off; off += (size_t)NPT*256;
    float* predh = w + off; off += (size_t)NPT*256;
    float* E1    = w + off; off += (size_t)NET*256;   // rel_enc (persistent)
    float* E2    = w + off; off += (size_t)NET*256;   // effect_rel / temp

    const int gP = (NPT + TM - 1) / TM;   // 63 blocks for particle GEMMs
    const int gE = (NET + TM - 1) / TM;   // 625 blocks for edge GEMMs

    k_detect<<<1, 256, 0, stream>>>(a_hist, 2000, dflag);
    k_prep<<<(NPT + 255)/256, 256, 0, stream>>>(a_hist, s_hist, s_delta, dflag, a_cur, s_cur, pe_in);
    k_topk<<<1000, 256, 0, stream>>>(a_cur, s_cur, send, flagp, re_in);

    // particle encoder
    k_gemm<0,false><<<gP, 256, 0, stream>>>(pe_in, nullptr, nullptr, pe_w0, pe_b0, dflag, nullptr, hp,   NPT, 16, 16, 16);
    k_gemm<0,false><<<gP, 256, 0, stream>>>(hp,    nullptr, nullptr, pe_w1, pe_b1, dflag, nullptr, penc, NPT, 256, 256, 256);

    // relation encoder (K=5 padded to 8 in A; W rows masked beyond 5)
    k_gemm<0,false><<<gE, 256, 0, stream>>>(re_in, nullptr, nullptr, re_w0, re_b0, dflag, nullptr, E1, NET, 8, 5, 8);
    k_gemm<0,false><<<gE, 256, 0, stream>>>(E1,    nullptr, nullptr, re_w1, re_b1, dflag, nullptr, E2, NET, 256, 256, 256);
    k_gemm<0,false><<<gE, 256, 0, stream>>>(E2,    nullptr, nullptr, re_w2, re_b2, dflag, nullptr, E1, NET, 256, 256, 256);
    // E1 = relation_encode (persistent across steps)

    // propagation step 1 (particle_effect = penc)
    k_gemm<1,false><<<gE, 256, 0, stream>>>(E1, penc, send, rp_w, rp_b, dflag, nullptr, E2, NET, 768, 768, 0);
    k_agg<<<NPT, 256, 0, stream>>>(E2, flagp, agg);
    k_gemm<2,true><<<gP, 256, 0, stream>>>(penc, agg, nullptr, pp_w, pp_b, dflag, penc, peffA, NPT, 512, 512, 0);
    // step 2
    k_gemm<1,false><<<gE, 256, 0, stream>>>(E1, peffA, send, rp_w, rp_b, dflag, nullptr, E2, NET, 768, 768, 0);
    k_agg<<<NPT, 256, 0, stream>>>(E2, flagp, agg);
    k_gemm<2,true><<<gP, 256, 0, stream>>>(penc, agg, nullptr, pp_w, pp_b, dflag, peffA, peffB, NPT, 512, 512, 0);
    // step 3
    k_gemm<1,false><<<gE, 256, 0, stream>>>(E1, peffB, send, rp_w, rp_b, dflag, nullptr, E2, NET, 768, 768, 0);
    k_agg<<<NPT, 256, 0, stream>>>(E2, flagp, agg);
    k_gemm<2,true><<<gP, 256, 0, stream>>>(penc, agg, nullptr, pp_w, pp_b, dflag, peffB, peffA, NPT, 512, 512, 0);

    // predictor
    k_gemm<0,false><<<gP, 256, 0, stream>>>(peffA, nullptr, nullptr, pr_w0, pr_b0, dflag, nullptr, predh, NPT, 256, 256, 256);
    k_final<<<(NPT*3 + 255)/256, 256, 0, stream>>>(predh, pr_w1, pr_b1, dflag, s_cur, (void*)d_out);
}

// Round 4
// 506.485 us; speedup vs baseline: 3.9551x; 2.9763x over previous
//
#include <hip/hip_runtime.h>
#include <hip/hip_bf16.h>

typedef unsigned short u16;
typedef unsigned int u32;

#define BATCH 4
#define NHIST 4
#define NPART 1000
#define NTOPK 10
#define NPT (BATCH*NPART)     // 4000 particles total
#define NET (NPT*NTOPK)       // 40000 edges total

typedef __bf16 b8v __attribute__((ext_vector_type(8)));
typedef float  f4v __attribute__((ext_vector_type(4)));

__device__ __forceinline__ float bf2f(u16 b){
    return __uint_as_float(((u32)b) << 16);
}
__device__ __forceinline__ u16 f2bf(float f){
    u32 u = __float_as_uint(f);
    u32 r = u + 0x7FFF + ((u >> 16) & 1);  // RNE
    return (u16)(r >> 16);
}
// dtype-agnostic input read: element i as float, per runtime flag
__device__ __forceinline__ float ldin(const void* p, size_t i, int isf32){
    return isf32 ? ((const float*)p)[i] : bf2f(((const u16*)p)[i]);
}

// ---------------- dtype probe: a_hist is Uniform[0,1) ----------------
__global__ void k_detect(const void* __restrict__ a_hist, int nu16, int* __restrict__ dflag)
{
    __shared__ int s;
    int t = threadIdx.x;
    if (t == 0) s = 0;
    __syncthreads();
    const u16* p = (const u16*)a_hist;
    int bad = 0;
    for (int i = t; i < nu16; i += 256) bad |= (p[i] & 0x8000) ? 1 : 0;
    if (bad) atomicOr(&s, 1);
    __syncthreads();
    if (t == 0) dflag[0] = s;   // 1 => inputs are float32
}

// ---------------- weight pre-swizzle into MFMA B-frag layout, bf16 ----------------
// Layout per 32-k chunk c: [tile t(16)][lane l(64)][j(8)] = W[c*32+(l>>4)*8+j][t*16+(l&15)]
// 8 weights, chunk counts {1,8,1,8,8,24,16,8} (K = {16,256,5,256,256,768,512,256})
__global__ void k_wxform(const void* w0, const void* w1, const void* w2, const void* w3,
                         const void* w4, const void* w5, const void* w6, const void* w7,
                         const int* __restrict__ dflag, u16* __restrict__ dst)
{
    const int nck[8] = {1,8,1,8,8,24,16,8};
    const int Ks[8]  = {16,256,5,256,256,768,512,256};
    const void* srcs[8] = {w0,w1,w2,w3,w4,w5,w6,w7};
    int isf32 = dflag[0];
    int b = blockIdx.x, wi = 0, c = b;
    while (c >= nck[wi]){ c -= nck[wi]; wi++; }
    const void* src = srcs[wi];
    int K = Ks[wi];
    size_t dbase = (size_t)blockIdx.x * 8192;
    int t = threadIdx.x;
    #pragma unroll 4
    for (int i = 0; i < 32; i++){
        int e = i*256 + t;
        int l = (e >> 3) & 63, j = e & 7, tg = e >> 9;
        int k = c*32 + (l >> 4)*8 + j;
        int n = tg*16 + (l & 15);
        float v = (k < K) ? ldin(src, (size_t)k*256 + n, isf32) : 0.f;
        dst[dbase + e] = f2bf(v);
    }
}

// ---------------- prep: a_cur, s_cur (f32), pe_in (bf16, stride 32) ----------------
__global__ void k_prep(const void* __restrict__ a_hist, const void* __restrict__ s_hist,
                       const void* __restrict__ s_delta, const int* __restrict__ dflag,
                       float* __restrict__ a_cur, float* __restrict__ s_cur,
                       u16* __restrict__ pe_in)
{
    int g = blockIdx.x * 256 + threadIdx.x;
    if (g >= NPT) return;
    int isf32 = dflag[0];
    int b = g / NPART, i = g - b * NPART;
    a_cur[g] = ldin(a_hist, (b*NHIST + NHIST-1)*NPART + i, isf32);
    #pragma unroll
    for (int d = 0; d < 3; d++)
        s_cur[g*3 + d] = ldin(s_hist, (size_t)((b*NHIST + NHIST-1)*NPART + i)*3 + d, isf32);
    #pragma unroll
    for (int h = 0; h < NHIST; h++){
        #pragma unroll
        for (int d = 0; d < 3; d++)
            pe_in[g*32 + h*3 + d] = f2bf(ldin(s_delta, (size_t)((b*NHIST + h)*NPART + i)*3 + d, isf32));
        pe_in[g*32 + 12 + h] = f2bf(ldin(a_hist, (b*NHIST + h)*NPART + i, isf32));
    }
    #pragma unroll
    for (int k = 16; k < 32; k++) pe_in[g*32 + k] = 0;
}

// ---------------- topk edge construction: one wave per receiver ----------------
__global__ __launch_bounds__(256) void k_topk(const float* __restrict__ a_cur,
        const float* __restrict__ s_cur,
        int* __restrict__ send, float* __restrict__ flag, u16* __restrict__ re_in)
{
    __shared__ float sx[NPART], sy[NPART], sz[NPART], sa[NPART];
    int b  = blockIdx.x / 250;
    int r0 = (blockIdx.x % 250) * 4;
    int t = threadIdx.x;
    int wid = t >> 6, lane = t & 63;
    for (int j = t; j < NPART; j += 256){
        int g = b*NPART + j;
        sx[j] = s_cur[g*3+0]; sy[j] = s_cur[g*3+1]; sz[j] = s_cur[g*3+2];
        sa[j] = a_cur[g];
    }
    __syncthreads();
    int i = r0 + wid;
    float xi = sx[i], yi = sy[i], zi = sz[i];
    float ai = sa[i];
    bool tool_i = ai > 0.5f;

    float bd[NTOPK]; int bj[NTOPK];
    #pragma unroll
    for (int k = 0; k < NTOPK; k++){ bd[k] = 3.0e38f; bj[k] = 1 << 30; }
    for (int j = lane; j < NPART; j += 64){
        float dx = xi - sx[j], dy = yi - sy[j], dz = zi - sz[j];
        float d = dx*dx + dy*dy + dz*dz;
        if (tool_i && (sa[j] > 0.5f)) d = 1.0e10f;
        if (d < bd[NTOPK-1]){
            float v = d; int vj = j;
            #pragma unroll
            for (int k = 0; k < NTOPK; k++){
                bool sw = v < bd[k];
                float tv = bd[k]; int tj = bj[k];
                if (sw){ bd[k] = v; bj[k] = vj; v = tv; vj = tj; }
            }
        }
    }
    float myd = 0.f; int myj = 0;
    #pragma unroll
    for (int r = 0; r < NTOPK; r++){
        float v = bd[0]; int vj = bj[0];
        #pragma unroll
        for (int s = 32; s > 0; s >>= 1){
            float ov = __shfl_xor(v, s);
            int   oj = __shfl_xor(vj, s);
            if (ov < v || (ov == v && oj < vj)){ v = ov; vj = oj; }
        }
        if (lane == r){ myd = v; myj = vj; }
        bool owner = (bd[0] == v) && (bj[0] == vj);
        if (owner){
            #pragma unroll
            for (int k = 0; k < NTOPK-1; k++){ bd[k] = bd[k+1]; bj[k] = bj[k+1]; }
            bd[NTOPK-1] = 3.0e38f; bj[NTOPK-1] = 1 << 30;
        }
    }
    if (lane < NTOPK){
        int gp = b*NPART + i;
        int re = gp*NTOPK + lane;
        int j = myj;
        float fl = (!tool_i && myd < 0.25f) ? 1.0f : 0.0f;
        send[re] = b*NPART + j;
        flag[re] = fl;
        u16* row = re_in + (size_t)re * 32;
        row[0] = f2bf(fl * ai);
        row[1] = f2bf(fl * sa[j]);
        row[2] = f2bf(fl * (xi - sx[j]));
        row[3] = f2bf(fl * (yi - sy[j]));
        row[4] = f2bf(fl * (zi - sz[j]));
        #pragma unroll
        for (int k = 5; k < 32; k++) row[k] = 0;
    }
}

// ---------------- MFMA GEMM: C = relu(A_gathered @ W + b [+ res]), N=256 ----------------
// 128x128 block tile, 4 waves (2x2), each wave 64x64 = 4x4 mfma_16x16x32 tiles.
// AMODE: 0=direct(lda), 1=RP gather (K=768), 2=PP concat (K=512). A,res,C bf16.
template<int AMODE, bool RES>
__global__ __launch_bounds__(256) void k_mgemm(
    const u16* __restrict__ A, const u16* __restrict__ X1,
    const int* __restrict__ send,
    const u16* __restrict__ Wsw, const void* __restrict__ Wb,
    const int* __restrict__ dflag,
    const u16* __restrict__ res,
    u16* __restrict__ C, int M, int K, int lda)
{
    __shared__ u16 a_lds[128*40];   // row-major, stride 40 bf16 (16B-aligned rows, 2-way bank at worst)
    __shared__ u16 w_lds[4096];     // 8 coltiles x 64 lanes x 8 (pre-swizzled B frags)
    const int isf32 = dflag[0];
    int t = threadIdx.x;
    int lane = t & 63, wave = t >> 6;
    int wm = wave >> 1, wn = wave & 1;
    int row0 = (blockIdx.x >> 1) * 128;
    int colhalf = blockIdx.x & 1;

    f4v acc[4][4];
    #pragma unroll
    for (int i = 0; i < 4; i++)
        #pragma unroll
        for (int j = 0; j < 4; j++) acc[i][j] = {0.f,0.f,0.f,0.f};

    int nkc = K >> 5;
    for (int kc = 0; kc < nkc; kc++){
        int kbase = kc * 32;
        // ---- stage A: 128 rows x 32 k bf16 ----
        #pragma unroll
        for (int it = 0; it < 2; it++){
            int e = t + it*256;          // 0..511
            int row = e >> 2;
            int k8 = (e & 3) * 8;
            int rg = row0 + row; if (rg >= M) rg = M - 1;
            int kg = kbase + k8;
            const u16* src;
            if (AMODE == 0){
                src = A + (size_t)rg * lda + kg;
            } else if (AMODE == 1){
                if (kg < 256)      src = A  + (size_t)rg * 256 + kg;
                else if (kg < 512) src = X1 + (size_t)(rg/10) * 256 + (kg - 256);
                else               src = X1 + (size_t)send[rg] * 256 + (kg - 512);
            } else {
                if (kg < 256)      src = A  + (size_t)rg * 256 + kg;
                else               src = X1 + (size_t)rg * 256 + (kg - 256);
            }
            *(uint4*)&a_lds[row*40 + k8] = *(const uint4*)src;
        }
        // ---- stage W: 8 coltiles x 64 x 8 bf16 (contiguous in swizzled global) ----
        {
            size_t wbase = ((size_t)kc*16 + colhalf*8) * 512;
            #pragma unroll
            for (int it = 0; it < 2; it++){
                int e = t + it*256;      // 0..511 uint4s
                *(uint4*)&w_lds[e*8] = *(const uint4*)(Wsw + wbase + (size_t)e*8);
            }
        }
        __syncthreads();
        // ---- frags + 16 MFMA ----
        b8v af[4], bf[4];
        #pragma unroll
        for (int i = 0; i < 4; i++)
            af[i] = *(const b8v*)&a_lds[(wm*64 + i*16 + (lane&15))*40 + (lane>>4)*8];
        #pragma unroll
        for (int j = 0; j < 4; j++)
            bf[j] = *(const b8v*)&w_lds[((wn*4 + j)*64 + lane)*8];
        #pragma unroll
        for (int i = 0; i < 4; i++)
            #pragma unroll
            for (int j = 0; j < 4; j++)
                acc[i][j] = __builtin_amdgcn_mfma_f32_16x16x32_bf16(af[i], bf[j], acc[i][j], 0, 0, 0);
        __syncthreads();
    }
    // ---- epilogue: bias (+res), relu, bf16 store ----
    float bias[4];
    #pragma unroll
    for (int j = 0; j < 4; j++){
        int col = colhalf*128 + wn*64 + j*16 + (lane & 15);
        bias[j] = ldin(Wb, col, isf32);
    }
    #pragma unroll
    for (int i = 0; i < 4; i++){
        int rbase = row0 + wm*64 + i*16 + (lane >> 4)*4;
        #pragma unroll
        for (int j = 0; j < 4; j++){
            int col = colhalf*128 + wn*64 + j*16 + (lane & 15);
            #pragma unroll
            for (int r = 0; r < 4; r++){
                int row = rbase + r;
                if (row < M){
                    float v = acc[i][j][r] + bias[j];
                    if (RES) v += bf2f(res[(size_t)row*256 + col]);
                    C[(size_t)row*256 + col] = f2bf(v > 0.f ? v : 0.f);
                }
            }
        }
    }
}

// ---------------- agg: per-particle flag-masked sum over its 10 edges (bf16 io) ----------------
__global__ void k_agg(const u16* __restrict__ effect_rel, const float* __restrict__ flag,
                      u16* __restrict__ agg)
{
    int g = blockIdx.x;
    int c = threadIdx.x;
    float s = 0.f;
    #pragma unroll
    for (int k = 0; k < NTOPK; k++){
        float f = flag[g*NTOPK + k];
        if (f > 0.f)
            s += bf2f(effect_rel[(size_t)(g*NTOPK + k) * 256 + c]);
    }
    agg[(size_t)g*256 + c] = f2bf(s);
}

// ---------------- final: predh @ pr_w1 + pr_b1 + s_cur -> out ----------------
__global__ void k_final(const u16* __restrict__ ph, const void* __restrict__ w1,
                        const void* __restrict__ b1, const int* __restrict__ dflag,
                        const float* __restrict__ s_cur, void* __restrict__ out)
{
    int idx = blockIdx.x * 256 + threadIdx.x;
    if (idx >= NPT * 3) return;
    int isf32 = dflag[0];
    int g = idx / 3, d = idx - g * 3;
    float s = ldin(b1, d, isf32) + s_cur[idx];
    const u16* row = ph + (size_t)g * 256;
    #pragma unroll 8
    for (int k = 0; k < 256; k++)
        s += bf2f(row[k]) * ldin(w1, k*3 + d, isf32);
    if (isf32) ((float*)out)[idx] = s;
    else       ((u16*)out)[idx]   = f2bf(s);
}

extern "C" void kernel_launch(void* const* d_in, const int* in_sizes, int n_in,
                              void* d_out, int out_size, void* d_ws, size_t ws_size,
                              hipStream_t stream) {
    const void* a_hist = d_in[0];
    const void* s_hist = d_in[1];
    const void* s_delta= d_in[2];
    const void* pe_w0 = d_in[3];  const void* pe_b0 = d_in[4];
    const void* pe_w1 = d_in[5];  const void* pe_b1 = d_in[6];
    const void* re_w0 = d_in[7];  const void* re_b0 = d_in[8];
    const void* re_w1 = d_in[9];  const void* re_b1 = d_in[10];
    const void* re_w2 = d_in[11]; const void* re_b2 = d_in[12];
    const void* rp_w  = d_in[13]; const void* rp_b  = d_in[14];
    const void* pp_w  = d_in[15]; const void* pp_b  = d_in[16];
    const void* pr_w0 = d_in[17]; const void* pr_b0 = d_in[18];
    const void* pr_w1 = d_in[19]; const void* pr_b1 = d_in[20];

    char* base = (char*)d_ws;
    size_t off = 0;
    auto alloc = [&](size_t bytes) -> char* {
        char* p = base + off;
        off += (bytes + 255) & ~(size_t)255;
        return p;
    };
    int*   dflag = (int*)  alloc(16);
    float* a_cur = (float*)alloc(NPT*4);
    float* s_cur = (float*)alloc(NPT*3*4);
    float* flagp = (float*)alloc(NET*4);
    int*   send  = (int*)  alloc(NET*4);
    u16* pe_in = (u16*)alloc((size_t)NPT*32*2);
    u16* re_in = (u16*)alloc((size_t)NET*32*2);
    u16* hp    = (u16*)alloc((size_t)NPT*256*2);
    u16* penc  = (u16*)alloc((size_t)NPT*256*2);
    u16* agg   = (u16*)alloc((size_t)NPT*256*2);
    u16* peffA = (u16*)alloc((size_t)NPT*256*2);
    u16* peffB = (u16*)alloc((size_t)NPT*256*2);
    u16* predh = (u16*)alloc((size_t)NPT*256*2);
    u16* E1    = (u16*)alloc((size_t)NET*256*2);
    u16* E2    = (u16*)alloc((size_t)NET*256*2);
    u16* wsw   = (u16*)alloc((size_t)74*8192*2);

    // swizzled-weight bases (chunks: pe_w0 1, pe_w1 8, re_w0 1, re_w1 8, re_w2 8, rp_w 24, pp_w 16, pr_w0 8)
    u16* sw_pe0 = wsw + (size_t) 0*8192;
    u16* sw_pe1 = wsw + (size_t) 1*8192;
    u16* sw_re0 = wsw + (size_t) 9*8192;
    u16* sw_re1 = wsw + (size_t)10*8192;
    u16* sw_re2 = wsw + (size_t)18*8192;
    u16* sw_rp  = wsw + (size_t)26*8192;
    u16* sw_pp  = wsw + (size_t)50*8192;
    u16* sw_pr0 = wsw + (size_t)66*8192;

    const int gE = 313*2;   // ceil(40000/128) row tiles x 2 col halves
    const int gP = 32*2;    // ceil(4000/128) x 2

    k_detect<<<1, 256, 0, stream>>>(a_hist, 2000, dflag);
    k_wxform<<<74, 256, 0, stream>>>(pe_w0, pe_w1, re_w0, re_w1, re_w2, rp_w, pp_w, pr_w0, dflag, wsw);
    k_prep<<<(NPT + 255)/256, 256, 0, stream>>>(a_hist, s_hist, s_delta, dflag, a_cur, s_cur, pe_in);
    k_topk<<<1000, 256, 0, stream>>>(a_cur, s_cur, send, flagp, re_in);

    // particle encoder
    k_mgemm<0,false><<<gP, 256, 0, stream>>>(pe_in, nullptr, nullptr, sw_pe0, pe_b0, dflag, nullptr, hp,   NPT, 32, 32);
    k_mgemm<0,false><<<gP, 256, 0, stream>>>(hp,    nullptr, nullptr, sw_pe1, pe_b1, dflag, nullptr, penc, NPT, 256, 256);

    // relation encoder
    k_mgemm<0,false><<<gE, 256, 0, stream>>>(re_in, nullptr, nullptr, sw_re0, re_b0, dflag, nullptr, E1, NET, 32, 32);
    k_mgemm<0,false><<<gE, 256, 0, stream>>>(E1,    nullptr, nullptr, sw_re1, re_b1, dflag, nullptr, E2, NET, 256, 256);
    k_mgemm<0,false><<<gE, 256, 0, stream>>>(E2,    nullptr, nullptr, sw_re2, re_b2, dflag, nullptr, E1, NET, 256, 256);
    // E1 = relation_encode (persistent across steps)

    // propagation step 1 (particle_effect = penc)
    k_mgemm<1,false><<<gE, 256, 0, stream>>>(E1, penc, send, sw_rp, rp_b, dflag, nullptr, E2, NET, 768, 0);
    k_agg<<<NPT, 256, 0, stream>>>(E2, flagp, agg);
    k_mgemm<2,true><<<gP, 256, 0, stream>>>(penc, agg, nullptr, sw_pp, pp_b, dflag, penc, peffA, NPT, 512, 0);
    // step 2
    k_mgemm<1,false><<<gE, 256, 0, stream>>>(E1, peffA, send, sw_rp, rp_b, dflag, nullptr, E2, NET, 768, 0);
    k_agg<<<NPT, 256, 0, stream>>>(E2, flagp, agg);
    k_mgemm<2,true><<<gP, 256, 0, stream>>>(penc, agg, nullptr, sw_pp, pp_b, dflag, peffA, peffB, NPT, 512, 0);
    // step 3
    k_mgemm<1,false><<<gE, 256, 0, stream>>>(E1, peffB, send, sw_rp, rp_b, dflag, nullptr, E2, NET, 768, 0);
    k_agg<<<NPT, 256, 0, stream>>>(E2, flagp, agg);
    k_mgemm<2,true><<<gP, 256, 0, stream>>>(penc, agg, nullptr, sw_pp, pp_b, dflag, peffB, peffA, NPT, 512, 0);

    // predictor
    k_mgemm<0,false><<<gP, 256, 0, stream>>>(peffA, nullptr, nullptr, sw_pr0, pr_b0, dflag, nullptr, predh, NPT, 256, 256);
    k_final<<<(NPT*3 + 255)/256, 256, 0, stream>>>(predh, pr_w1, pr_b1, dflag, s_cur, (void*)d_out);
}